// Round 6
// baseline (1372.096 us; speedup 1.0000x reference)
//
#include <hip/hip_runtime.h>
#include <hip/hip_bf16.h>
#include <cstdint>
#include <cstddef>

#define NE  16
#define HD  1024
#define ID  4096
#define TPE 2048
#define TOKENS 32768

typedef __attribute__((ext_vector_type(8))) short short8;     // 8 bf16 (4 VGPRs)
typedef __attribute__((ext_vector_type(4))) float f32x4;      // MFMA acc
typedef __attribute__((ext_vector_type(4))) unsigned short u16x4;
typedef __attribute__((ext_vector_type(8))) unsigned short u16x8;

static __device__ __forceinline__ unsigned short f2b(float f) {
    __bf16 h = (__bf16)f;                       // RNE fp32->bf16
    return __builtin_bit_cast(unsigned short, h);
}

// wave-level async global->LDS, 16B/lane: LDS dest = uniform base + lane*16
// (linear). Swizzle applied on the GLOBAL source (rule #21).
#define GLOAD16(gsrc, ldsbase)                                                  \
    __builtin_amdgcn_global_load_lds(                                           \
        (const __attribute__((address_space(1))) unsigned int*)(gsrc),          \
        (__attribute__((address_space(3))) unsigned int*)(ldsbase), 16, 0, 0)

#define MFMA16(a, b, c) __builtin_amdgcn_mfma_f32_16x16x32_bf16((a), (b), (c), 0, 0, 0)

// ---------------------------------------------------------------------------
// Pre-pass 1: hs fp32 -> bf16 (linear)
// ---------------------------------------------------------------------------
__global__ void k_f2b(const float* __restrict__ src, unsigned short* __restrict__ dst, int n4)
{
    int i = blockIdx.x * blockDim.x + threadIdx.x;
    int stride = gridDim.x * blockDim.x;
    for (; i < n4; i += stride) {
        float4 v = *(const float4*)(src + (size_t)i * 4);
        u16x4 b = { f2b(v.x), f2b(v.y), f2b(v.z), f2b(v.w) };
        *(u16x4*)(dst + (size_t)i * 4) = b;
    }
}

// ---------------------------------------------------------------------------
// Pre-pass 2: weight convert+transpose. src fp32 [e][K][N] (global e),
// dst bf16 [eL][N][K] (chunk-local). 64x64 tiles via LDS.
// ---------------------------------------------------------------------------
__global__ __launch_bounds__(256) void k_transpose(const float* __restrict__ src,
                                                   unsigned short* __restrict__ dst,
                                                   int K, int N, int e0)
{
    __shared__ unsigned short LT[64][72];
    const int t  = threadIdx.x;
    const int eL = blockIdx.z;
    const float* s = src + (size_t)(e0 + eL) * K * N
                         + (size_t)(blockIdx.y * 64) * N + blockIdx.x * 64;
    unsigned short* d = dst + (size_t)eL * N * K
                            + (size_t)(blockIdx.x * 64) * K + blockIdx.y * 64;
    #pragma unroll
    for (int i = 0; i < 4; ++i) {
        int row = i * 16 + (t >> 4);
        int c4  = (t & 15) * 4;
        float4 v = *(const float4*)(s + (size_t)row * N + c4);
        LT[c4 + 0][row] = f2b(v.x);
        LT[c4 + 1][row] = f2b(v.y);
        LT[c4 + 2][row] = f2b(v.z);
        LT[c4 + 3][row] = f2b(v.w);
    }
    __syncthreads();
    #pragma unroll
    for (int i = 0; i < 2; ++i) {
        int n  = i * 32 + (t >> 3);
        int k8 = (t & 7) * 8;
        u16x8 v = *(const u16x8*)&LT[n][k8];
        *(u16x8*)(d + (size_t)n * K + k8) = v;
    }
}

// ---------------------------------------------------------------------------
// Fine-phase (m201-style) 256x256 GEMM + SwiGLU.
// Per K-tile: 4 phases {stage 1 unit, ds_read subtile, lgkm0+SB, setprio MFMA,
// barrier}. Units: A split by fm-half rows {0-63,128-191} / {64-127,192-255};
// B split c 0-127 / 128-255. Stage ledger (iter t): A1(t+1)@ph1 -> buf[nxt];
// A0(t+2)@ph2, Bh0(t+2)@ph3, Bh1(t+2)@ph4 -> dead regions of buf[cur].
// Counted waits: vmcnt(10) end-ph2 (A1(t) resident), vmcnt(8) end-ph4
// (B(t+1)+A0(t+1) resident). Never vmcnt(0) in-loop.
// ---------------------------------------------------------------------------
__global__ __launch_bounds__(512, 2) void k_gemm1(const unsigned short* __restrict__ hsB,
                                                  const unsigned short* __restrict__ gupT,
                                                  unsigned short* __restrict__ gated,
                                                  int e0)
{
    __shared__ unsigned short As[2][256 * 64];
    __shared__ unsigned short Bs[2][256 * 64];
    const int NT = HD / 64;   // 16

    const int t    = threadIdx.x;
    const int lane = t & 63;
    const int w    = t >> 6;
    const int wr   = w >> 2;          // 0..1
    const int wc   = w & 3;           // 0..3
    const int eL   = blockIdx.z;
    const int e    = e0 + eL;
    const int n0g  = blockIdx.x * 128;   // gated col base
    const int m0   = blockIdx.y * 256;

    const unsigned short* gA  = hsB  + (size_t)(e * TPE + m0) * HD;
    const unsigned short* gBt = gupT + (size_t)eL * (2 * ID) * HD;

    f32x4 acc[8][4];
    #pragma unroll
    for (int i = 0; i < 8; ++i)
        #pragma unroll
        for (int j = 0; j < 4; ++j)
            acc[i][j] = f32x4{0.f, 0.f, 0.f, 0.f};

    auto stageA = [&](int buf, int kt, int fmh) {   // 16KB unit, 2 gloads
        #pragma unroll
        for (int i = 0; i < 2; ++i) {
            int r0  = fmh * 64 + w * 8 + i * 128;   // wave-uniform
            int row = r0 + (lane >> 3);
            int sl  = lane & 7;
            GLOAD16(gA + (size_t)row * HD + kt * 64 + ((sl ^ (row & 7)) << 3),
                    &As[buf][r0 * 64]);
        }
    };
    auto stageB = [&](int buf, int kt, int half) {  // 16KB unit, 2 gloads
        #pragma unroll
        for (int i = 0; i < 2; ++i) {
            int c0 = half * 128 + w * 8 + i * 64;   // wave-uniform
            int c  = c0 + (lane >> 3);
            int sl = lane & 7;
            int g  = c >> 5;
            int grow = ((g & 1) ? ID : 0) + n0g + ((g >> 1) << 5) + (c & 31);
            GLOAD16(gBt + (size_t)grow * HD + kt * 64 + ((sl ^ (c & 7)) << 3),
                    &Bs[buf][c0 * 64]);
        }
    };

    // prologue: tiles 0 and 1 (unit order matches steady-state numbering)
    stageA(0, 0, 0);  stageB(0, 0, 0);  stageB(0, 0, 1);   // A0(0), B(0)
    stageA(0, 0, 1);                                       // A1(0)
    stageA(1, 1, 0);  stageB(1, 1, 0);  stageB(1, 1, 1);   // A0(1), B(1)
    asm volatile("s_waitcnt vmcnt(8)" ::: "memory");       // A0(0)+B(0) landed
    __builtin_amdgcn_s_barrier();

    for (int kt = 0; kt < NT; ++kt) {
        const int cur = kt & 1, nxt = cur ^ 1;
        const unsigned short* Ab = &As[cur][0];
        const unsigned short* Bb = &Bs[cur][0];
        const int ktn  = (kt + 1 < NT) ? kt + 1 : NT - 1;  // clamped (keeps vmcnt exact)
        const int ktn2 = (kt + 2 < NT) ? kt + 2 : NT - 1;

        short8 av[8], bv[8];

        // ---- phase 1: stage A1(kt+1); read av(fmh0)+bv(fn01); MFMA Q00 ----
        stageA(nxt, ktn, 1);
        #pragma unroll
        for (int f = 0; f < 4; ++f)
            #pragma unroll
            for (int ks = 0; ks < 2; ++ks) {
                int row = wr * 128 + f * 16 + (lane & 15);
                int sl  = ks * 4 + (lane >> 4);
                av[f * 2 + ks] = *(const short8*)&Ab[row * 64 + ((sl ^ (row & 7)) << 3)];
            }
        #pragma unroll
        for (int fn = 0; fn < 2; ++fn)
            #pragma unroll
            for (int ks = 0; ks < 2; ++ks) {
                int c  = wc * 64 + fn * 16 + (lane & 15);
                int sl = ks * 4 + (lane >> 4);
                bv[fn * 2 + ks] = *(const short8*)&Bb[c * 64 + ((sl ^ (c & 7)) << 3)];
            }
        asm volatile("s_waitcnt lgkmcnt(0)" ::: "memory");
        __builtin_amdgcn_sched_barrier(0);
        __builtin_amdgcn_s_setprio(1);
        #pragma unroll
        for (int f = 0; f < 4; ++f)
            #pragma unroll
            for (int fn = 0; fn < 2; ++fn)
                #pragma unroll
                for (int ks = 0; ks < 2; ++ks)
                    acc[f][fn] = MFMA16(av[f * 2 + ks], bv[fn * 2 + ks], acc[f][fn]);
        __builtin_amdgcn_s_setprio(0);
        __builtin_amdgcn_s_barrier();

        // ---- phase 2: stage A0(kt+2); read bv(fn23); MFMA Q01; vmcnt(10) ----
        stageA(cur, ktn2, 0);
        #pragma unroll
        for (int fn = 2; fn < 4; ++fn)
            #pragma unroll
            for (int ks = 0; ks < 2; ++ks) {
                int c  = wc * 64 + fn * 16 + (lane & 15);
                int sl = ks * 4 + (lane >> 4);
                bv[fn * 2 + ks] = *(const short8*)&Bb[c * 64 + ((sl ^ (c & 7)) << 3)];
            }
        asm volatile("s_waitcnt lgkmcnt(0)" ::: "memory");
        __builtin_amdgcn_sched_barrier(0);
        __builtin_amdgcn_s_setprio(1);
        #pragma unroll
        for (int f = 0; f < 4; ++f)
            #pragma unroll
            for (int fn = 2; fn < 4; ++fn)
                #pragma unroll
                for (int ks = 0; ks < 2; ++ks)
                    acc[f][fn] = MFMA16(av[f * 2 + ks], bv[fn * 2 + ks], acc[f][fn]);
        __builtin_amdgcn_s_setprio(0);
        asm volatile("s_waitcnt vmcnt(10)" ::: "memory");   // A1(kt) resident
        __builtin_amdgcn_s_barrier();

        // ---- phase 3: stage Bh0(kt+2); read av(fmh1); MFMA Q10 ----
        stageB(cur, ktn2, 0);
        #pragma unroll
        for (int f = 0; f < 4; ++f)
            #pragma unroll
            for (int ks = 0; ks < 2; ++ks) {
                int row = wr * 128 + 64 + f * 16 + (lane & 15);
                int sl  = ks * 4 + (lane >> 4);
                av[f * 2 + ks] = *(const short8*)&Ab[row * 64 + ((sl ^ (row & 7)) << 3)];
            }
        asm volatile("s_waitcnt lgkmcnt(0)" ::: "memory");
        __builtin_amdgcn_sched_barrier(0);
        __builtin_amdgcn_s_setprio(1);
        #pragma unroll
        for (int f = 0; f < 4; ++f)
            #pragma unroll
            for (int fn = 0; fn < 2; ++fn)
                #pragma unroll
                for (int ks = 0; ks < 2; ++ks)
                    acc[4 + f][fn] = MFMA16(av[f * 2 + ks], bv[fn * 2 + ks], acc[4 + f][fn]);
        __builtin_amdgcn_s_setprio(0);
        __builtin_amdgcn_s_barrier();

        // ---- phase 4: stage Bh1(kt+2); MFMA Q11; vmcnt(8) ----
        stageB(cur, ktn2, 1);
        __builtin_amdgcn_s_setprio(1);
        #pragma unroll
        for (int f = 0; f < 4; ++f)
            #pragma unroll
            for (int fn = 2; fn < 4; ++fn)
                #pragma unroll
                for (int ks = 0; ks < 2; ++ks)
                    acc[4 + f][fn] = MFMA16(av[f * 2 + ks], bv[fn * 2 + ks], acc[4 + f][fn]);
        __builtin_amdgcn_s_setprio(0);
        asm volatile("s_waitcnt vmcnt(8)" ::: "memory");    // B(kt+1)+A0(kt+1) resident
        __builtin_amdgcn_s_barrier();
    }
    asm volatile("s_waitcnt vmcnt(0)" ::: "memory");        // drain DMAs before exit

    // ---- SwiGLU epilogue: fn (gate) pairs with fn+2 (up), same cols ----
    unsigned short* g0 = gated + ((size_t)eL * TPE + m0) * ID;
    const int rq = (lane >> 4) << 2;   // C/D: row=(lane>>4)*4+r, col=lane&15 (m89)
    const int cl = lane & 15;
    #pragma unroll
    for (int fm = 0; fm < 8; ++fm) {
        #pragma unroll
        for (int fp = 0; fp < 2; ++fp) {
            f32x4 g = acc[fm][fp];
            f32x4 u = acc[fm][fp + 2];
            #pragma unroll
            for (int r = 0; r < 4; ++r) {
                float gv  = g[r];
                float val = u[r] * gv / (1.0f + __expf(-gv));
                int row = wr * 128 + fm * 16 + rq + r;
                int col = n0g + wc * 32 + fp * 16 + cl;
                g0[(size_t)row * ID + col] = f2b(val);
            }
        }
    }
}

// ---------------------------------------------------------------------------
// GEMM2: gated bf16 @ dwnT bf16 -> out fp32. Same fine-phase pipeline.
// ---------------------------------------------------------------------------
__global__ __launch_bounds__(512, 2) void k_gemm2(const unsigned short* __restrict__ gated,
                                                  const unsigned short* __restrict__ dwnT,
                                                  float* __restrict__ out,
                                                  int e0)
{
    __shared__ unsigned short As[2][256 * 64];
    __shared__ unsigned short Bs[2][256 * 64];
    const int NT = ID / 64;   // 64

    const int t    = threadIdx.x;
    const int lane = t & 63;
    const int w    = t >> 6;
    const int wr   = w >> 2;
    const int wc   = w & 3;
    const int eL   = blockIdx.z;
    const int e    = e0 + eL;
    const int n0   = blockIdx.x * 256;
    const int m0   = blockIdx.y * 256;

    const unsigned short* gA  = gated + ((size_t)eL * TPE + m0) * ID;
    const unsigned short* gBt = dwnT  + (size_t)eL * HD * ID;

    f32x4 acc[8][4];
    #pragma unroll
    for (int i = 0; i < 8; ++i)
        #pragma unroll
        for (int j = 0; j < 4; ++j)
            acc[i][j] = f32x4{0.f, 0.f, 0.f, 0.f};

    auto stageA = [&](int buf, int kt, int fmh) {
        #pragma unroll
        for (int i = 0; i < 2; ++i) {
            int r0  = fmh * 64 + w * 8 + i * 128;
            int row = r0 + (lane >> 3);
            int sl  = lane & 7;
            GLOAD16(gA + (size_t)row * ID + kt * 64 + ((sl ^ (row & 7)) << 3),
                    &As[buf][r0 * 64]);
        }
    };
    auto stageB = [&](int buf, int kt, int half) {
        #pragma unroll
        for (int i = 0; i < 2; ++i) {
            int c0 = half * 128 + w * 8 + i * 64;
            int c  = c0 + (lane >> 3);
            int sl = lane & 7;
            GLOAD16(gBt + (size_t)(n0 + c) * ID + kt * 64 + ((sl ^ (c & 7)) << 3),
                    &Bs[buf][c0 * 64]);
        }
    };

    stageA(0, 0, 0);  stageB(0, 0, 0);  stageB(0, 0, 1);
    stageA(0, 0, 1);
    stageA(1, 1, 0);  stageB(1, 1, 0);  stageB(1, 1, 1);
    asm volatile("s_waitcnt vmcnt(8)" ::: "memory");
    __builtin_amdgcn_s_barrier();

    for (int kt = 0; kt < NT; ++kt) {
        const int cur = kt & 1, nxt = cur ^ 1;
        const unsigned short* Ab = &As[cur][0];
        const unsigned short* Bb = &Bs[cur][0];
        const int ktn  = (kt + 1 < NT) ? kt + 1 : NT - 1;
        const int ktn2 = (kt + 2 < NT) ? kt + 2 : NT - 1;

        short8 av[8], bv[8];

        // ---- phase 1 ----
        stageA(nxt, ktn, 1);
        #pragma unroll
        for (int f = 0; f < 4; ++f)
            #pragma unroll
            for (int ks = 0; ks < 2; ++ks) {
                int row = wr * 128 + f * 16 + (lane & 15);
                int sl  = ks * 4 + (lane >> 4);
                av[f * 2 + ks] = *(const short8*)&Ab[row * 64 + ((sl ^ (row & 7)) << 3)];
            }
        #pragma unroll
        for (int fn = 0; fn < 2; ++fn)
            #pragma unroll
            for (int ks = 0; ks < 2; ++ks) {
                int c  = wc * 64 + fn * 16 + (lane & 15);
                int sl = ks * 4 + (lane >> 4);
                bv[fn * 2 + ks] = *(const short8*)&Bb[c * 64 + ((sl ^ (c & 7)) << 3)];
            }
        asm volatile("s_waitcnt lgkmcnt(0)" ::: "memory");
        __builtin_amdgcn_sched_barrier(0);
        __builtin_amdgcn_s_setprio(1);
        #pragma unroll
        for (int f = 0; f < 4; ++f)
            #pragma unroll
            for (int fn = 0; fn < 2; ++fn)
                #pragma unroll
                for (int ks = 0; ks < 2; ++ks)
                    acc[f][fn] = MFMA16(av[f * 2 + ks], bv[fn * 2 + ks], acc[f][fn]);
        __builtin_amdgcn_s_setprio(0);
        __builtin_amdgcn_s_barrier();

        // ---- phase 2 ----
        stageA(cur, ktn2, 0);
        #pragma unroll
        for (int fn = 2; fn < 4; ++fn)
            #pragma unroll
            for (int ks = 0; ks < 2; ++ks) {
                int c  = wc * 64 + fn * 16 + (lane & 15);
                int sl = ks * 4 + (lane >> 4);
                bv[fn * 2 + ks] = *(const short8*)&Bb[c * 64 + ((sl ^ (c & 7)) << 3)];
            }
        asm volatile("s_waitcnt lgkmcnt(0)" ::: "memory");
        __builtin_amdgcn_sched_barrier(0);
        __builtin_amdgcn_s_setprio(1);
        #pragma unroll
        for (int f = 0; f < 4; ++f)
            #pragma unroll
            for (int fn = 2; fn < 4; ++fn)
                #pragma unroll
                for (int ks = 0; ks < 2; ++ks)
                    acc[f][fn] = MFMA16(av[f * 2 + ks], bv[fn * 2 + ks], acc[f][fn]);
        __builtin_amdgcn_s_setprio(0);
        asm volatile("s_waitcnt vmcnt(10)" ::: "memory");
        __builtin_amdgcn_s_barrier();

        // ---- phase 3 ----
        stageB(cur, ktn2, 0);
        #pragma unroll
        for (int f = 0; f < 4; ++f)
            #pragma unroll
            for (int ks = 0; ks < 2; ++ks) {
                int row = wr * 128 + 64 + f * 16 + (lane & 15);
                int sl  = ks * 4 + (lane >> 4);
                av[f * 2 + ks] = *(const short8*)&Ab[row * 64 + ((sl ^ (row & 7)) << 3)];
            }
        asm volatile("s_waitcnt lgkmcnt(0)" ::: "memory");
        __builtin_amdgcn_sched_barrier(0);
        __builtin_amdgcn_s_setprio(1);
        #pragma unroll
        for (int f = 0; f < 4; ++f)
            #pragma unroll
            for (int fn = 0; fn < 2; ++fn)
                #pragma unroll
                for (int ks = 0; ks < 2; ++ks)
                    acc[4 + f][fn] = MFMA16(av[f * 2 + ks], bv[fn * 2 + ks], acc[4 + f][fn]);
        __builtin_amdgcn_s_setprio(0);
        __builtin_amdgcn_s_barrier();

        // ---- phase 4 ----
        stageB(cur, ktn2, 1);
        __builtin_amdgcn_s_setprio(1);
        #pragma unroll
        for (int f = 0; f < 4; ++f)
            #pragma unroll
            for (int fn = 2; fn < 4; ++fn)
                #pragma unroll
                for (int ks = 0; ks < 2; ++ks)
                    acc[4 + f][fn] = MFMA16(av[f * 2 + ks], bv[fn * 2 + ks], acc[4 + f][fn]);
        __builtin_amdgcn_s_setprio(0);
        asm volatile("s_waitcnt vmcnt(8)" ::: "memory");
        __builtin_amdgcn_s_barrier();
    }
    asm volatile("s_waitcnt vmcnt(0)" ::: "memory");

    float* o0 = out + (size_t)(e * TPE + m0) * HD;
    const int rq = (lane >> 4) << 2;
    const int cl = lane & 15;
    #pragma unroll
    for (int fm = 0; fm < 8; ++fm) {
        #pragma unroll
        for (int fn = 0; fn < 4; ++fn) {
            #pragma unroll
            for (int r = 0; r < 4; ++r) {
                int row = wr * 128 + fm * 16 + rq + r;
                int col = n0 + wc * 64 + fn * 16 + cl;
                o0[(size_t)row * HD + col] = acc[fm][fn][r];
            }
        }
    }
}

extern "C" void kernel_launch(void* const* d_in, const int* in_sizes, int n_in,
                              void* d_out, int out_size, void* d_ws, size_t ws_size,
                              hipStream_t stream)
{
    (void)in_sizes; (void)n_in; (void)out_size;
    const float* hs  = (const float*)d_in[0];
    const float* gup = (const float*)d_in[1];
    const float* dwn = (const float*)d_in[2];
    float* out = (float*)d_out;

    const size_t SZ_HSB   = (size_t)TOKENS * HD * 2;          // 67.1 MB
    const size_t SZ_GUPT  = (size_t)2 * ID * HD * 2;          // 16.78 MB / expert
    const size_t SZ_DWNT  = (size_t)HD * ID * 2;              //  8.39 MB / expert
    const size_t SZ_GATED = (size_t)TPE * ID * 2;             // 16.78 MB / expert
    const size_t perExp   = SZ_GUPT + SZ_DWNT + SZ_GATED;     // 41.94 MB

    int G = (ws_size > SZ_HSB) ? (int)((ws_size - SZ_HSB) / perExp) : 1;
    if (G < 1) G = 1;
    if (G > NE) G = NE;

    unsigned short* hsB   = (unsigned short*)d_ws;
    unsigned short* gupT  = (unsigned short*)((char*)d_ws + SZ_HSB);
    unsigned short* dwnT  = (unsigned short*)((char*)d_ws + SZ_HSB + (size_t)G * SZ_GUPT);
    unsigned short* gated = (unsigned short*)((char*)d_ws + SZ_HSB + (size_t)G * (SZ_GUPT + SZ_DWNT));

    k_f2b<<<2048, 256, 0, stream>>>(hs, hsB, TOKENS * HD / 4);

    for (int e0 = 0; e0 < NE; e0 += G) {
        int ne = NE - e0;
        if (ne > G) ne = G;
        k_transpose<<<dim3((2 * ID) / 64, HD / 64, ne), 256, 0, stream>>>(gup, gupT, HD, 2 * ID, e0);
        k_transpose<<<dim3(HD / 64, ID / 64, ne), 256, 0, stream>>>(dwn, dwnT, ID, HD, e0);
        k_gemm1<<<dim3(ID / 128, TPE / 256, ne), 512, 0, stream>>>(hsB, gupT, gated, e0);
        k_gemm2<<<dim3(HD / 256, TPE / 256, ne), 512, 0, stream>>>(gated, dwnT, out, e0);
    }
}

// Round 7
// 1284.110 us; speedup vs baseline: 1.0685x; 1.0685x over previous
//
#include <hip/hip_runtime.h>
#include <hip/hip_bf16.h>
#include <cstdint>
#include <cstddef>

#define NE  16
#define HD  1024
#define ID  4096
#define TPE 2048
#define TOKENS 32768

typedef __attribute__((ext_vector_type(8))) short short8;     // 8 bf16 (4 VGPRs)
typedef __attribute__((ext_vector_type(4))) float f32x4;      // MFMA acc
typedef __attribute__((ext_vector_type(4))) unsigned short u16x4;
typedef __attribute__((ext_vector_type(8))) unsigned short u16x8;

static __device__ __forceinline__ unsigned short f2b(float f) {
    __bf16 h = (__bf16)f;                       // RNE fp32->bf16
    return __builtin_bit_cast(unsigned short, h);
}

// wave-level async global->LDS, 16B/lane: LDS dest = uniform base + lane*16
// (linear). Swizzle applied on the GLOBAL source (rule #21).
#define GLOAD16(gsrc, ldsbase)                                                  \
    __builtin_amdgcn_global_load_lds(                                           \
        (const __attribute__((address_space(1))) unsigned int*)(gsrc),          \
        (__attribute__((address_space(3))) unsigned int*)(ldsbase), 16, 0, 0)

#define MFMA16(a, b, c) __builtin_amdgcn_mfma_f32_16x16x32_bf16((a), (b), (c), 0, 0, 0)

// ---------------------------------------------------------------------------
// Pre-pass 1: hs fp32 -> bf16 (linear)
// ---------------------------------------------------------------------------
__global__ void k_f2b(const float* __restrict__ src, unsigned short* __restrict__ dst, int n4)
{
    int i = blockIdx.x * blockDim.x + threadIdx.x;
    int stride = gridDim.x * blockDim.x;
    for (; i < n4; i += stride) {
        float4 v = *(const float4*)(src + (size_t)i * 4);
        u16x4 b = { f2b(v.x), f2b(v.y), f2b(v.z), f2b(v.w) };
        *(u16x4*)(dst + (size_t)i * 4) = b;
    }
}

// ---------------------------------------------------------------------------
// Pre-pass 2: weight convert+transpose. src fp32 [e][K][N] (global e),
// dst bf16 [eL][N][K] (chunk-local). 64x64 tiles via LDS.
// ---------------------------------------------------------------------------
__global__ __launch_bounds__(256) void k_transpose(const float* __restrict__ src,
                                                   unsigned short* __restrict__ dst,
                                                   int K, int N, int e0)
{
    __shared__ unsigned short LT[64][72];
    const int t  = threadIdx.x;
    const int eL = blockIdx.z;
    const float* s = src + (size_t)(e0 + eL) * K * N
                         + (size_t)(blockIdx.y * 64) * N + blockIdx.x * 64;
    unsigned short* d = dst + (size_t)eL * N * K
                            + (size_t)(blockIdx.x * 64) * K + blockIdx.y * 64;
    #pragma unroll
    for (int i = 0; i < 4; ++i) {
        int row = i * 16 + (t >> 4);
        int c4  = (t & 15) * 4;
        float4 v = *(const float4*)(s + (size_t)row * N + c4);
        LT[c4 + 0][row] = f2b(v.x);
        LT[c4 + 1][row] = f2b(v.y);
        LT[c4 + 2][row] = f2b(v.z);
        LT[c4 + 3][row] = f2b(v.w);
    }
    __syncthreads();
    #pragma unroll
    for (int i = 0; i < 2; ++i) {
        int n  = i * 32 + (t >> 3);
        int k8 = (t & 7) * 8;
        u16x8 v = *(const u16x8*)&LT[n][k8];
        *(u16x8*)(d + (size_t)n * K + k8) = v;
    }
}

// ---------------------------------------------------------------------------
// GEMM1 + SwiGLU, 256x256 tile, 8 waves, register read-ahead pipeline.
// Per kt (2 barriers, counted waits, nothing exposed):
//   issue ks1(kt) reads -> Q ; lgkm(12) [P=ks0(kt) ready] ; MFMA P
//   lgkm(0)+barrier [buf released] ; STAGE(kt+2)->buf[cur]
//   vmcnt(8)+barrier [tile kt+1 resident] ; issue ks0(kt+1) reads -> P
//   MFMA Q (no wait: Q complete since lgkm(0))
// ---------------------------------------------------------------------------
__global__ __launch_bounds__(512, 2) void k_gemm1(const unsigned short* __restrict__ hsB,
                                                  const unsigned short* __restrict__ gupT,
                                                  unsigned short* __restrict__ gated,
                                                  int e0)
{
    __shared__ unsigned short As[2][256 * 64];
    __shared__ unsigned short Bs[2][256 * 64];
    const int NT = HD / 64;   // 16

    const int t    = threadIdx.x;
    const int lane = t & 63;
    const int w    = t >> 6;
    const int wr   = w >> 2;          // 0..1
    const int wc   = w & 3;           // 0..3
    const int eL   = blockIdx.z;
    const int e    = e0 + eL;
    const int n0g  = blockIdx.x * 128;   // gated col base
    const int m0   = blockIdx.y * 256;

    const unsigned short* gA  = hsB  + (size_t)(e * TPE + m0) * HD;
    const unsigned short* gBt = gupT + (size_t)eL * (2 * ID) * HD;

    f32x4 acc[8][4];
    #pragma unroll
    for (int i = 0; i < 8; ++i)
        #pragma unroll
        for (int j = 0; j < 4; ++j)
            acc[i][j] = f32x4{0.f, 0.f, 0.f, 0.f};

    auto STAGE = [&](int buf, int kt) {            // 8 gloads exactly
        #pragma unroll
        for (int i = 0; i < 4; ++i) {              // A: 256 rows x 64 k
            int idx = i * 512 + t;
            int row = idx >> 3, sl = idx & 7;
            GLOAD16(gA + (size_t)row * HD + kt * 64 + ((sl ^ (row & 7)) << 3),
                    &As[buf][(size_t)(i * 512 + (t & ~63)) * 8]);
        }
        #pragma unroll
        for (int i = 0; i < 4; ++i) {              // B: 256 rows (gate/up x32 groups)
            int idx = i * 512 + t;
            int c = idx >> 3, sl = idx & 7;
            int g = c >> 5, j = c & 31;
            int grow = ((g & 1) ? ID : 0) + n0g + ((g >> 1) << 5) + (c & 31);
            (void)j;
            GLOAD16(gBt + (size_t)grow * HD + kt * 64 + ((sl ^ (c & 7)) << 3),
                    &Bs[buf][(size_t)(i * 512 + (t & ~63)) * 8]);
        }
    };

    short8 avP[8], bvP[4], avQ[8], bvQ[4];

    auto READ_A = [&](const unsigned short* Ab, int ks, short8* av) {
        #pragma unroll
        for (int f = 0; f < 8; ++f) {
            int row = wr * 128 + f * 16 + (lane & 15);
            int sl  = ks * 4 + (lane >> 4);
            av[f] = *(const short8*)&Ab[row * 64 + ((sl ^ (row & 7)) << 3)];
        }
    };
    auto READ_B = [&](const unsigned short* Bb, int ks, short8* bv) {
        #pragma unroll
        for (int fn = 0; fn < 4; ++fn) {
            int c  = wc * 64 + fn * 16 + (lane & 15);
            int sl = ks * 4 + (lane >> 4);
            bv[fn] = *(const short8*)&Bb[c * 64 + ((sl ^ (c & 7)) << 3)];
        }
    };

    // ---- prologue ----
    STAGE(0, 0);
    STAGE(1, 1);
    asm volatile("s_waitcnt vmcnt(8)" ::: "memory");   // tile 0 resident
    __builtin_amdgcn_s_barrier();
    READ_A(&As[0][0], 0, avP);  READ_B(&Bs[0][0], 0, bvP);   // ks0(0) -> P

    for (int kt = 0; kt < NT; ++kt) {
        const int cur = kt & 1;
        const unsigned short* Ab  = &As[cur][0];
        const unsigned short* Bb  = &Bs[cur][0];
        const unsigned short* Abn = &As[cur ^ 1][0];
        const unsigned short* Bbn = &Bs[cur ^ 1][0];
        const int ktn2 = (kt + 2 < NT) ? kt + 2 : NT - 1;   // clamp keeps vmcnt exact

        // issue ks1(kt) -> Q, then MFMA ks0 (P ready after lgkm(12))
        READ_A(Ab, 1, avQ);  READ_B(Bb, 1, bvQ);
        asm volatile("s_waitcnt lgkmcnt(12)" ::: "memory");
        __builtin_amdgcn_sched_barrier(0);
        __builtin_amdgcn_s_setprio(1);
        #pragma unroll
        for (int f = 0; f < 8; ++f)
            #pragma unroll
            for (int fn = 0; fn < 4; ++fn)
                acc[f][fn] = MFMA16(avP[f], bvP[fn], acc[f][fn]);
        __builtin_amdgcn_s_setprio(0);

        // release buf[cur], stage kt+2 into it, make tile kt+1 visible
        asm volatile("s_waitcnt lgkmcnt(0)" ::: "memory");
        __builtin_amdgcn_s_barrier();
        STAGE(cur, ktn2);
        asm volatile("s_waitcnt vmcnt(8)" ::: "memory");
        __builtin_amdgcn_s_barrier();
        __builtin_amdgcn_sched_barrier(0);

        // issue ks0(kt+1) -> P (overlaps MFMA ks1; dead regs on last iter)
        READ_A(Abn, 0, avP);  READ_B(Bbn, 0, bvP);

        __builtin_amdgcn_s_setprio(1);
        #pragma unroll
        for (int f = 0; f < 8; ++f)
            #pragma unroll
            for (int fn = 0; fn < 4; ++fn)
                acc[f][fn] = MFMA16(avQ[f], bvQ[fn], acc[f][fn]);
        __builtin_amdgcn_s_setprio(0);
    }
    asm volatile("s_waitcnt vmcnt(0)" ::: "memory");   // drain DMAs before exit

    // ---- SwiGLU epilogue: fn (gate) pairs with fn+2 (up), same cols ----
    unsigned short* g0 = gated + ((size_t)eL * TPE + m0) * ID;
    const int rq = (lane >> 4) << 2;   // C/D: row=(lane>>4)*4+r, col=lane&15 (m89)
    const int cl = lane & 15;
    #pragma unroll
    for (int fm = 0; fm < 8; ++fm) {
        #pragma unroll
        for (int fp = 0; fp < 2; ++fp) {
            f32x4 g = acc[fm][fp];
            f32x4 u = acc[fm][fp + 2];
            #pragma unroll
            for (int r = 0; r < 4; ++r) {
                float gv  = g[r];
                float val = u[r] * gv / (1.0f + __expf(-gv));
                int row = wr * 128 + fm * 16 + rq + r;
                int col = n0g + wc * 32 + fp * 16 + cl;
                g0[(size_t)row * ID + col] = f2b(val);
            }
        }
    }
}

// ---------------------------------------------------------------------------
// GEMM2: gated bf16 @ dwnT bf16 -> out fp32. Same read-ahead pipeline.
// ---------------------------------------------------------------------------
__global__ __launch_bounds__(512, 2) void k_gemm2(const unsigned short* __restrict__ gated,
                                                  const unsigned short* __restrict__ dwnT,
                                                  float* __restrict__ out,
                                                  int e0)
{
    __shared__ unsigned short As[2][256 * 64];
    __shared__ unsigned short Bs[2][256 * 64];
    const int NT = ID / 64;   // 64

    const int t    = threadIdx.x;
    const int lane = t & 63;
    const int w    = t >> 6;
    const int wr   = w >> 2;
    const int wc   = w & 3;
    const int eL   = blockIdx.z;
    const int e    = e0 + eL;
    const int n0   = blockIdx.x * 256;
    const int m0   = blockIdx.y * 256;

    const unsigned short* gA  = gated + ((size_t)eL * TPE + m0) * ID;
    const unsigned short* gBt = dwnT  + (size_t)eL * HD * ID;

    f32x4 acc[8][4];
    #pragma unroll
    for (int i = 0; i < 8; ++i)
        #pragma unroll
        for (int j = 0; j < 4; ++j)
            acc[i][j] = f32x4{0.f, 0.f, 0.f, 0.f};

    auto STAGE = [&](int buf, int kt) {
        #pragma unroll
        for (int i = 0; i < 4; ++i) {
            int idx = i * 512 + t;
            int row = idx >> 3, sl = idx & 7;
            GLOAD16(gA + (size_t)row * ID + kt * 64 + ((sl ^ (row & 7)) << 3),
                    &As[buf][(size_t)(i * 512 + (t & ~63)) * 8]);
        }
        #pragma unroll
        for (int i = 0; i < 4; ++i) {
            int idx = i * 512 + t;
            int c = idx >> 3, sl = idx & 7;
            GLOAD16(gBt + (size_t)(n0 + c) * ID + kt * 64 + ((sl ^ (c & 7)) << 3),
                    &Bs[buf][(size_t)(i * 512 + (t & ~63)) * 8]);
        }
    };

    short8 avP[8], bvP[4], avQ[8], bvQ[4];

    auto READ_A = [&](const unsigned short* Ab, int ks, short8* av) {
        #pragma unroll
        for (int f = 0; f < 8; ++f) {
            int row = wr * 128 + f * 16 + (lane & 15);
            int sl  = ks * 4 + (lane >> 4);
            av[f] = *(const short8*)&Ab[row * 64 + ((sl ^ (row & 7)) << 3)];
        }
    };
    auto READ_B = [&](const unsigned short* Bb, int ks, short8* bv) {
        #pragma unroll
        for (int fn = 0; fn < 4; ++fn) {
            int c  = wc * 64 + fn * 16 + (lane & 15);
            int sl = ks * 4 + (lane >> 4);
            bv[fn] = *(const short8*)&Bb[c * 64 + ((sl ^ (c & 7)) << 3)];
        }
    };

    STAGE(0, 0);
    STAGE(1, 1);
    asm volatile("s_waitcnt vmcnt(8)" ::: "memory");
    __builtin_amdgcn_s_barrier();
    READ_A(&As[0][0], 0, avP);  READ_B(&Bs[0][0], 0, bvP);

    for (int kt = 0; kt < NT; ++kt) {
        const int cur = kt & 1;
        const unsigned short* Ab  = &As[cur][0];
        const unsigned short* Bb  = &Bs[cur][0];
        const unsigned short* Abn = &As[cur ^ 1][0];
        const unsigned short* Bbn = &Bs[cur ^ 1][0];
        const int ktn2 = (kt + 2 < NT) ? kt + 2 : NT - 1;

        READ_A(Ab, 1, avQ);  READ_B(Bb, 1, bvQ);
        asm volatile("s_waitcnt lgkmcnt(12)" ::: "memory");
        __builtin_amdgcn_sched_barrier(0);
        __builtin_amdgcn_s_setprio(1);
        #pragma unroll
        for (int f = 0; f < 8; ++f)
            #pragma unroll
            for (int fn = 0; fn < 4; ++fn)
                acc[f][fn] = MFMA16(avP[f], bvP[fn], acc[f][fn]);
        __builtin_amdgcn_s_setprio(0);

        asm volatile("s_waitcnt lgkmcnt(0)" ::: "memory");
        __builtin_amdgcn_s_barrier();
        STAGE(cur, ktn2);
        asm volatile("s_waitcnt vmcnt(8)" ::: "memory");
        __builtin_amdgcn_s_barrier();
        __builtin_amdgcn_sched_barrier(0);

        READ_A(Abn, 0, avP);  READ_B(Bbn, 0, bvP);

        __builtin_amdgcn_s_setprio(1);
        #pragma unroll
        for (int f = 0; f < 8; ++f)
            #pragma unroll
            for (int fn = 0; fn < 4; ++fn)
                acc[f][fn] = MFMA16(avQ[f], bvQ[fn], acc[f][fn]);
        __builtin_amdgcn_s_setprio(0);
    }
    asm volatile("s_waitcnt vmcnt(0)" ::: "memory");

    float* o0 = out + (size_t)(e * TPE + m0) * HD;
    const int rq = (lane >> 4) << 2;
    const int cl = lane & 15;
    #pragma unroll
    for (int fm = 0; fm < 8; ++fm) {
        #pragma unroll
        for (int fn = 0; fn < 4; ++fn) {
            #pragma unroll
            for (int r = 0; r < 4; ++r) {
                int row = wr * 128 + fm * 16 + rq + r;
                int col = n0 + wc * 64 + fn * 16 + cl;
                o0[(size_t)row * HD + col] = acc[fm][fn][r];
            }
        }
    }
}

extern "C" void kernel_launch(void* const* d_in, const int* in_sizes, int n_in,
                              void* d_out, int out_size, void* d_ws, size_t ws_size,
                              hipStream_t stream)
{
    (void)in_sizes; (void)n_in; (void)out_size;
    const float* hs  = (const float*)d_in[0];
    const float* gup = (const float*)d_in[1];
    const float* dwn = (const float*)d_in[2];
    float* out = (float*)d_out;

    const size_t SZ_HSB   = (size_t)TOKENS * HD * 2;          // 67.1 MB
    const size_t SZ_GUPT  = (size_t)2 * ID * HD * 2;          // 16.78 MB / expert
    const size_t SZ_DWNT  = (size_t)HD * ID * 2;              //  8.39 MB / expert
    const size_t SZ_GATED = (size_t)TPE * ID * 2;             // 16.78 MB / expert
    const size_t perExp   = SZ_GUPT + SZ_DWNT + SZ_GATED;     // 41.94 MB

    int G = (ws_size > SZ_HSB) ? (int)((ws_size - SZ_HSB) / perExp) : 1;
    if (G < 1) G = 1;
    if (G > NE) G = NE;

    unsigned short* hsB   = (unsigned short*)d_ws;
    unsigned short* gupT  = (unsigned short*)((char*)d_ws + SZ_HSB);
    unsigned short* dwnT  = (unsigned short*)((char*)d_ws + SZ_HSB + (size_t)G * SZ_GUPT);
    unsigned short* gated = (unsigned short*)((char*)d_ws + SZ_HSB + (size_t)G * (SZ_GUPT + SZ_DWNT));

    k_f2b<<<2048, 256, 0, stream>>>(hs, hsB, TOKENS * HD / 4);

    for (int e0 = 0; e0 < NE; e0 += G) {
        int ne = NE - e0;
        if (ne > G) ne = G;
        k_transpose<<<dim3((2 * ID) / 64, HD / 64, ne), 256, 0, stream>>>(gup, gupT, HD, 2 * ID, e0);
        k_transpose<<<dim3(HD / 64, ID / 64, ne), 256, 0, stream>>>(dwn, dwnT, ID, HD, e0);
        k_gemm1<<<dim3(ID / 128, TPE / 256, ne), 512, 0, stream>>>(hsB, gupT, gated, e0);
        k_gemm2<<<dim3(HD / 256, TPE / 256, ne), 512, 0, stream>>>(gated, dwnT, out, e0);
    }
}